// Round 6
// baseline (240.423 us; speedup 1.0000x reference)
//
#include <hip/hip_runtime.h>
#include <hip/hip_bf16.h>
#include <cstdint>
#include <cstddef>

#define B_ 4
#define S_ 1024
#define D_ 1024
#define H_ 16
#define DEPTH_ 64
#define M_ (B_*S_)   // 4096 rows total

typedef __attribute__((ext_vector_type(4))) float f32x4;
typedef __attribute__((ext_vector_type(8))) __bf16 bf16x8;
typedef __attribute__((ext_vector_type(8))) unsigned short u16x8;
typedef __attribute__((ext_vector_type(4))) unsigned short u16x4;

typedef const __attribute__((address_space(1))) unsigned int GU32;
typedef __attribute__((address_space(3))) unsigned int LU32;

__device__ __forceinline__ unsigned short f2bf(float f) {
  unsigned int u = __builtin_bit_cast(unsigned int, f);
  u += 0x7FFFu + ((u >> 16) & 1u);   // round-to-nearest-even
  return (unsigned short)(u >> 16);
}

__device__ __forceinline__ float bf2f(unsigned short v) {
  unsigned int u = (unsigned int)v << 16;
  return __builtin_bit_cast(float, u);
}

// ---------------- f32 -> bf16 converts: ONE launch for all 7 tensors -------
struct CvtAll { const float* s[7]; unsigned short* d[7]; };

__device__ __forceinline__ void cvt_body(const float* __restrict__ s,
                                         unsigned short* __restrict__ d, int i) {
  const f32x4* sp = (const f32x4*)s + (size_t)i * 2;
  f32x4 a = sp[0], b = sp[1];
  u16x8 o;
  o[0]=f2bf(a[0]); o[1]=f2bf(a[1]); o[2]=f2bf(a[2]); o[3]=f2bf(a[3]);
  o[4]=f2bf(b[0]); o[5]=f2bf(b[1]); o[6]=f2bf(b[2]); o[7]=f2bf(b[3]);
  *((u16x8*)d + i) = o;
}

// grid 8192: q,k,v = 2048 blocks each; 4 weights = 512 each. No tails.
__global__ void cvt_all_kernel(CvtAll a) {
  int bi = blockIdx.x, seg, i;
  if (bi < 6144) { seg = bi >> 11;              i = ((bi & 2047) << 8) + threadIdx.x; }
  else           { int t = bi - 6144; seg = 3 + (t >> 9); i = ((t & 511) << 8) + threadIdx.x; }
  cvt_body(a.s[seg], a.d[seg], i);
}

// ---------------- NT GEMM body: C[m][n] = (sum_k A[m][k]*B[n][k] + bias)*scale
__device__ __forceinline__ void gemm_body(
    const unsigned short* __restrict__ A,
    const unsigned short* __restrict__ Bm,
    unsigned short* __restrict__ Obf,
    float* __restrict__ Of32,
    const float* __restrict__ bias,
    int N, int K, float scale, int biasRow, int m0, int n0)
{
  __shared__ unsigned short As[128*32];
  __shared__ unsigned short Bs[128*32];
  const int tid  = threadIdx.x;
  const int lane = tid & 63;
  const int w    = tid >> 6;
  const int wm   = w >> 1, wn = w & 1;
  const int fr   = lane & 15, kg = lane >> 4;

  f32x4 acc[4][4];
  #pragma unroll
  for (int i = 0; i < 4; ++i)
    #pragma unroll
    for (int j = 0; j < 4; ++j)
      acc[i][j] = (f32x4)0.0f;

  const int o0 = tid * 16,        o1 = (256 + tid) * 16;
  const int r0 = o0 >> 6,         c0 = (o0 & 63) >> 1;
  const int r1 = o1 >> 6,         c1 = (o1 & 63) >> 1;
  const int lds0 = (w * 64) * 16;
  const int lds1 = (256 + w * 64) * 16;

  const int nkt = K >> 5;
  for (int kt = 0; kt < nkt; ++kt) {
    const int kk = kt * 32;
    __builtin_amdgcn_global_load_lds((GU32*)(A  + (size_t)(m0 + r0) * K + kk + c0),
                                     (LU32*)((char*)As + lds0), 16, 0, 0);
    __builtin_amdgcn_global_load_lds((GU32*)(A  + (size_t)(m0 + r1) * K + kk + c1),
                                     (LU32*)((char*)As + lds1), 16, 0, 0);
    __builtin_amdgcn_global_load_lds((GU32*)(Bm + (size_t)(n0 + r0) * K + kk + c0),
                                     (LU32*)((char*)Bs + lds0), 16, 0, 0);
    __builtin_amdgcn_global_load_lds((GU32*)(Bm + (size_t)(n0 + r1) * K + kk + c1),
                                     (LU32*)((char*)Bs + lds1), 16, 0, 0);
    __syncthreads();

    bf16x8 af[4], bf[4];
    #pragma unroll
    for (int i = 0; i < 4; ++i)
      af[i] = *(const bf16x8*)&As[(wm * 64 + i * 16 + fr) * 32 + kg * 8];
    #pragma unroll
    for (int j = 0; j < 4; ++j)
      bf[j] = *(const bf16x8*)&Bs[(wn * 64 + j * 16 + fr) * 32 + kg * 8];
    #pragma unroll
    for (int i = 0; i < 4; ++i)
      #pragma unroll
      for (int j = 0; j < 4; ++j)
        acc[i][j] = __builtin_amdgcn_mfma_f32_16x16x32_bf16(af[i], bf[j], acc[i][j], 0, 0, 0);
    __syncthreads();
  }

  #pragma unroll
  for (int i = 0; i < 4; ++i) {
    const int rowb = m0 + wm * 64 + i * 16 + kg * 4;
    #pragma unroll
    for (int j = 0; j < 4; ++j) {
      const int col = n0 + wn * 64 + j * 16 + fr;
      const float bcol = biasRow ? 0.0f : bias[col];
      #pragma unroll
      for (int r = 0; r < 4; ++r) {
        const int row = rowb + r;
        const float bv = biasRow ? bias[row] : bcol;
        const float val = (acc[i][j][r] + bv) * scale;
        if (Obf) Obf[(size_t)row * N + col] = f2bf(val);
        else     Of32[(size_t)row * N + col] = val;
      }
    }
  }
}

struct GemmSet { const unsigned short* A; const unsigned short* Bm;
                 unsigned short* O; const float* bias; };

__launch_bounds__(256)
__global__ void qkv_gemm(GemmSet s0, GemmSet s1, GemmSet s2) {
  const int z = blockIdx.y;
  GemmSet s = (z == 0) ? s0 : (z == 1) ? s1 : s2;
  int m0, n0, N; float scale; int biasRow;
  if (z < 2) { m0 = (blockIdx.x & 31) * 128; n0 = (blockIdx.x >> 5) * 128;
               N = D_; scale = (z == 0) ? 0.125f : 1.0f; biasRow = 0; }
  else       { m0 = (blockIdx.x & 7) * 128;  n0 = (blockIdx.x >> 3) * 128;
               N = M_; scale = 1.0f; biasRow = 1; }
  gemm_body(s.A, s.Bm, s.O, nullptr, s.bias, N, D_, scale, biasRow, m0, n0);
}

__launch_bounds__(256)
__global__ void dense_gemm(const unsigned short* __restrict__ A,
                           const unsigned short* __restrict__ Bm,
                           float* __restrict__ O, const float* __restrict__ bias) {
  gemm_body(A, Bm, nullptr, O, bias, D_, D_, 1.0f, 0,
            blockIdx.x * 128, blockIdx.y * 128);
}

// ---------------- fused attention v6: single k-loop, counted vmcnt ---------
// grid 2048 blocks, 512 threads (8 waves). Per block: 32 q-rows, k = 1024 in
// 16 tiles of 64. Per iteration t: QK(t) + exp/P-write(t) + PV(t-1), with
// K/adj(t+2), V(t+1) staged via global_load_lds AFTER the read-release
// barrier; waits are counted (vmcnt(3)), never drained, so every staging
// load has ~2 iterations of flight time. No max-subtraction (softmax is
// shift-invariant; logits are small) -> no rescale, PV fuses into the loop.
// LDS (117 KB): K dbuf 16K | V dbuf 16K | adj dbuf 16K | P 64K | mask 4K | sums
__launch_bounds__(512, 2)
__global__ void attn_kernel(const unsigned short* __restrict__ qp,
                            const unsigned short* __restrict__ kp,
                            const unsigned short* __restrict__ vt,
                            const float* __restrict__ mask,
                            const float* __restrict__ adjoin,
                            float* __restrict__ attn_out,
                            unsigned short* __restrict__ ctx)
{
  __shared__ __align__(16) char L[119808];
  char* const Kb0 = L;                     // K tiles [0,16K)
  char* const Vb0 = L + 16384;             // V tiles [16K,32K)
  char* const Ab0 = L + 32768;             // adj tiles [32K,48K)
  char* const Pb  = L + 49152;             // P bf16 [32][1024] swizzled, 64K
  char* const Mbb = L + 114688;            // mask f32 [1024], 4K
  float* const ssum = (float*)(L + 118784);

  const int tid = threadIdx.x, lane = tid & 63, w = tid >> 6;
  const int fr = lane & 15, kg = lane >> 4;
  const int fm = w >> 2, ks4 = w & 3, fd = w & 3;
  const int q  = fm * 16 + fr;             // this thread's q column (rel)
  const int R0 = ks4 * 16 + fr;            // K-frag row within 64-k tile
  const int frsw = (fr & 7) << 4;          // XOR swizzle (row&7 == fr&7)

  // XCD map: XCD x=i&7 owns bh in [8x,8x+8); adjoin tile reused by 8 heads.
  const int i_ = blockIdx.x;
  const int bh = (i_ & 7) * 8 + ((i_ >> 3) & 7);
  const int qt = i_ >> 6;
  const int b = bh >> 4, h = bh & 15;
  const int q0 = qt * 32;

  const char* kbB_  = (const char*)(kp + (size_t)b * S_ * D_ + h * DEPTH_);
  const char* adjB_ = (const char*)(adjoin + (size_t)b * S_ * S_ + (size_t)q0 * S_);
  const char* vB_   = (const char*)(vt + (size_t)h * DEPTH_ * M_ + (size_t)b * S_);
  const char* mbB_  = (const char*)(mask + (size_t)b * S_);

  // stage-lane geometry (LDS dest is linear: wave base + lane*16)
  const int sR8 = (w << 3) + (lane >> 3);            // 0..63 rows (K/V tiles)
  const int sSw8 = ((lane & 7) << 4) ^ ((sR8 & 7) << 4);
  const int sR4 = (w << 2) + (lane >> 4);            // 0..31 rows (adj tile)
  const int sSw4 = ((lane & 15) << 4) ^ ((sR4 & 7) << 4);
  const int ldsW = w << 10;                          // wave byte base in tile

  // Q fragments (B-operand), loop-invariant (retire before/with tile 0)
  const unsigned short* qrow = qp + ((size_t)b * S_ + q0 + q) * D_ + h * DEPTH_;
  bf16x8 qf0 = *(const bf16x8*)&qrow[kg * 8];
  bf16x8 qf1 = *(const bf16x8*)&qrow[32 + kg * 8];

  // ---- prologue staging: mask, K0, A0, V0, K1, A1 (issue order matters)
  if (w < 4)
    __builtin_amdgcn_global_load_lds((GU32*)(mbB_ + (w << 10) + lane * 16),
                                     (LU32*)(Mbb + (w << 10)), 16, 0, 0);
  __builtin_amdgcn_global_load_lds((GU32*)(kbB_ + (size_t)sR8 * 2048 + sSw8),
                                   (LU32*)(Kb0 + ldsW), 16, 0, 0);
  __builtin_amdgcn_global_load_lds((GU32*)(adjB_ + (size_t)sR4 * 4096 + sSw4),
                                   (LU32*)(Ab0 + ldsW), 16, 0, 0);
  __builtin_amdgcn_global_load_lds((GU32*)(vB_ + (size_t)sR8 * 8192 + sSw8),
                                   (LU32*)(Vb0 + ldsW), 16, 0, 0);
  __builtin_amdgcn_global_load_lds((GU32*)(kbB_ + (size_t)(64 + sR8) * 2048 + sSw8),
                                   (LU32*)(Kb0 + 8192 + ldsW), 16, 0, 0);
  __builtin_amdgcn_global_load_lds((GU32*)(adjB_ + (size_t)sR4 * 4096 + 256 + sSw4),
                                   (LU32*)(Ab0 + 8192 + ldsW), 16, 0, 0);

  f32x4 cacc = (f32x4)0.0f;
  float ls = 0.0f;

  #pragma unroll
  for (int t = 0; t < 16; ++t) {
    // tile t (K,adj) and tile t-1 (V) are the 3 oldest in-flight loads
    asm volatile("s_waitcnt vmcnt(3)" ::: "memory");
    __builtin_amdgcn_s_barrier();
    __builtin_amdgcn_sched_barrier(0);

    const char* kb_ = Kb0 + (t & 1) * 8192;
    const char* ab_ = Ab0 + (t & 1) * 8192;

    // QK(t): S^T strip, d=64 via 2 chained MFMAs
    bf16x8 kf0 = *(const bf16x8*)(kb_ + R0 * 128 + ((kg * 16) ^ frsw));
    bf16x8 kf1 = *(const bf16x8*)(kb_ + R0 * 128 + ((64 + kg * 16) ^ frsw));
    f32x4 sacc = (f32x4)0.0f;
    sacc = __builtin_amdgcn_mfma_f32_16x16x32_bf16(kf0, qf0, sacc, 0, 0, 0);
    sacc = __builtin_amdgcn_mfma_f32_16x16x32_bf16(kf1, qf1, sacc, 0, 0, 0);
    f32x4 a4 = *(const f32x4*)(ab_ + q * 256 + ((ks4 * 64 + kg * 16) ^ frsw));
    f32x4 m4 = *(const f32x4*)(Mbb + t * 256 + (ks4 * 16 + kg * 4) * 4);

    // PV(t-1): overlaps QK latency; reads P written last iteration
    if (t >= 1) {
      const char* vb_ = Vb0 + ((t - 1) & 1) * 8192;
      bf16x8 vf0 = *(const bf16x8*)(vb_ + (fd * 16 + fr) * 128 + ((kg * 16) ^ frsw));
      bf16x8 vf1 = *(const bf16x8*)(vb_ + (fd * 16 + fr) * 128 + ((64 + kg * 16) ^ frsw));
      bf16x8 pf0 = *(const bf16x8*)(Pb + q * 2048 + (((t - 1) * 128 + kg * 16) ^ frsw));
      bf16x8 pf1 = *(const bf16x8*)(Pb + q * 2048 + (((t - 1) * 128 + 64 + kg * 16) ^ frsw));
      cacc = __builtin_amdgcn_mfma_f32_16x16x32_bf16(vf0, pf0, cacc, 0, 0, 0);
      cacc = __builtin_amdgcn_mfma_f32_16x16x32_bf16(vf1, pf1, cacc, 0, 0, 0);
    }

    // exp(t) -> bf16 P (swizzled LDS) + running sum
    f32x4 p;
    #pragma unroll
    for (int r = 0; r < 4; ++r)
      p[r] = __expf(sacc[r] + a4[r] + m4[r] * (-1e9f));
    ls += (p[0] + p[1]) + (p[2] + p[3]);
    u16x4 pk;
    pk[0] = f2bf(p[0]); pk[1] = f2bf(p[1]); pk[2] = f2bf(p[2]); pk[3] = f2bf(p[3]);
    *(u16x4*)(Pb + q * 2048 + ((t * 128 + ks4 * 32 + kg * 8) ^ frsw)) = pk;

    // read-release barrier: P(t) visible; K/adj(t), V(t-1) free to overwrite
    asm volatile("s_waitcnt lgkmcnt(0)" ::: "memory");
    __builtin_amdgcn_s_barrier();
    __builtin_amdgcn_sched_barrier(0);

    // stage K/adj(t+2) and V(t+1), clamped (duplicates keep vmcnt invariant)
    const int t2 = (t + 2 > 15) ? 15 : t + 2;
    const int tv = (t + 1 > 15) ? 15 : t + 1;
    __builtin_amdgcn_global_load_lds(
        (GU32*)(kbB_ + (size_t)(t2 * 64 + sR8) * 2048 + sSw8),
        (LU32*)(Kb0 + (t & 1) * 8192 + ldsW), 16, 0, 0);
    __builtin_amdgcn_global_load_lds(
        (GU32*)(adjB_ + (size_t)sR4 * 4096 + t2 * 256 + sSw4),
        (LU32*)(Ab0 + (t & 1) * 8192 + ldsW), 16, 0, 0);
    __builtin_amdgcn_global_load_lds(
        (GU32*)(vB_ + (size_t)sR8 * 8192 + tv * 128 + sSw8),
        (LU32*)(Vb0 + ((t + 1) & 1) * 8192 + ldsW), 16, 0, 0);
  }

  // ---- epilogue PV(15): V(15) is among the 3 oldest outstanding loads
  asm volatile("s_waitcnt vmcnt(3)" ::: "memory");
  __builtin_amdgcn_s_barrier();
  __builtin_amdgcn_sched_barrier(0);
  {
    const char* vb_ = Vb0 + 8192;   // 15 & 1
    bf16x8 vf0 = *(const bf16x8*)(vb_ + (fd * 16 + fr) * 128 + ((kg * 16) ^ frsw));
    bf16x8 vf1 = *(const bf16x8*)(vb_ + (fd * 16 + fr) * 128 + ((64 + kg * 16) ^ frsw));
    bf16x8 pf0 = *(const bf16x8*)(Pb + q * 2048 + ((15 * 128 + kg * 16) ^ frsw));
    bf16x8 pf1 = *(const bf16x8*)(Pb + q * 2048 + ((15 * 128 + 64 + kg * 16) ^ frsw));
    cacc = __builtin_amdgcn_mfma_f32_16x16x32_bf16(vf0, pf0, cacc, 0, 0, 0);
    cacc = __builtin_amdgcn_mfma_f32_16x16x32_bf16(vf1, pf1, cacc, 0, 0, 0);
  }

  // ---- row sums: reduce over kg lanes, then across the 4 k-strip waves
  ls += __shfl_xor(ls, 16);
  ls += __shfl_xor(ls, 32);
  if (lane < 16) ssum[(fm * 16 + lane) * 4 + ks4] = ls;
  __syncthreads();

  // ---- ctx store
  {
    f32x4 s4 = *(const f32x4*)&ssum[q * 4];
    const float giC = 1.0f / ((s4[0] + s4[1]) + (s4[2] + s4[3]));
    u16x4 cv;
    #pragma unroll
    for (int r = 0; r < 4; ++r) cv[r] = f2bf(cacc[r] * giC);
    *(u16x4*)&ctx[((size_t)b * S_ + q0 + q) * D_ + h * DEPTH_ + fd * 16 + kg * 4] = cv;
  }

  // ---- attn store: 4 rows per wave from P-LDS, full-line f32 stores
  #pragma unroll
  for (int j = 0; j < 4; ++j) {
    const int row = w * 4 + j;
    f32x4 t4 = *(const f32x4*)&ssum[row * 4];
    const float g = 1.0f / ((t4[0] + t4[1]) + (t4[2] + t4[3]));
    const char* pr = Pb + row * 2048;
    const int rs = (row & 7) << 4;
    float* ao = attn_out + ((size_t)bh * S_ + q0 + row) * S_;
    #pragma unroll
    for (int half = 0; half < 2; ++half) {
      u16x8 pv = *(const u16x8*)(pr + ((half * 1024 + lane * 16) ^ rs));
      f32x4 o0, o1;
      #pragma unroll
      for (int e = 0; e < 4; ++e) { o0[e] = bf2f(pv[e]) * g; o1[e] = bf2f(pv[4 + e]) * g; }
      *(f32x4*)(ao + half * 512 + lane * 8) = o0;
      *(f32x4*)(ao + half * 512 + lane * 8 + 4) = o1;
    }
  }
}

// ---------------- launcher ----------------
extern "C" void kernel_launch(void* const* d_in, const int* in_sizes, int n_in,
                              void* d_out, int out_size, void* d_ws, size_t ws_size,
                              hipStream_t stream)
{
  const float* v_in   = (const float*)d_in[0];
  const float* k_in   = (const float*)d_in[1];
  const float* q_in   = (const float*)d_in[2];
  const float* mask   = (const float*)d_in[3];
  const float* adjoin = (const float*)d_in[4];
  const float* wq_w   = (const float*)d_in[5];
  const float* wq_b   = (const float*)d_in[6];
  const float* wk_w   = (const float*)d_in[7];
  const float* wk_b   = (const float*)d_in[8];
  const float* wv_w   = (const float*)d_in[9];
  const float* wv_b   = (const float*)d_in[10];
  const float* wd_w   = (const float*)d_in[11];
  const float* wd_b   = (const float*)d_in[12];

  unsigned short* xq  = (unsigned short*)d_ws;
  unsigned short* xk  = xq  + (size_t)M_ * D_;
  unsigned short* xv  = xk  + (size_t)M_ * D_;
  unsigned short* wqb = xv  + (size_t)M_ * D_;
  unsigned short* wkb = wqb + (size_t)D_ * D_;
  unsigned short* wvb = wkb + (size_t)D_ * D_;
  unsigned short* wdb = wvb + (size_t)D_ * D_;
  unsigned short* qp  = wdb + (size_t)D_ * D_;
  unsigned short* kp  = qp  + (size_t)M_ * D_;
  unsigned short* vt  = kp  + (size_t)M_ * D_;
  unsigned short* ctx = vt  + (size_t)M_ * D_;

  float* out  = (float*)d_out;                       // [B,S,D]
  float* attn = out + (size_t)B_ * S_ * D_;          // [B,H,S,S]

  CvtAll ca;
  ca.s[0] = q_in; ca.s[1] = k_in; ca.s[2] = v_in;
  ca.s[3] = wq_w; ca.s[4] = wk_w; ca.s[5] = wv_w; ca.s[6] = wd_w;
  ca.d[0] = xq;   ca.d[1] = xk;   ca.d[2] = xv;
  ca.d[3] = wqb;  ca.d[4] = wkb;  ca.d[5] = wvb;  ca.d[6] = wdb;
  cvt_all_kernel<<<8192, 256, 0, stream>>>(ca);

  GemmSet sq{xq,  wqb, qp, wq_b};
  GemmSet sk{xk,  wkb, kp, wk_b};
  GemmSet sv{wvb, xv,  vt, wv_b};
  qkv_gemm<<<dim3(256, 3), 256, 0, stream>>>(sq, sk, sv);

  attn_kernel<<<B_ * H_ * (S_ / 32), 512, 0, stream>>>(qp, kp, vt, mask, adjoin, attn, ctx);

  dense_gemm<<<dim3(32, 8), 256, 0, stream>>>(ctx, wdb, out, wd_b);
}

// Round 8
// 196.723 us; speedup vs baseline: 1.2221x; 1.2221x over previous
//
#include <hip/hip_runtime.h>
#include <hip/hip_bf16.h>
#include <cstdint>
#include <cstddef>

#define B_ 4
#define S_ 1024
#define D_ 1024
#define H_ 16
#define DEPTH_ 64
#define M_ (B_*S_)   // 4096 rows total

typedef __attribute__((ext_vector_type(4))) float f32x4;
typedef __attribute__((ext_vector_type(8))) __bf16 bf16x8;
typedef __attribute__((ext_vector_type(8))) unsigned short u16x8;
typedef __attribute__((ext_vector_type(4))) unsigned short u16x4;

typedef const __attribute__((address_space(1))) unsigned int GU32;
typedef __attribute__((address_space(3))) unsigned int LU32;

__device__ __forceinline__ unsigned short f2bf(float f) {
  unsigned int u = __builtin_bit_cast(unsigned int, f);
  u += 0x7FFFu + ((u >> 16) & 1u);   // round-to-nearest-even
  return (unsigned short)(u >> 16);
}

__device__ __forceinline__ float bf2f(unsigned short v) {
  unsigned int u = (unsigned int)v << 16;
  return __builtin_bit_cast(float, u);
}

// ---------------- f32 -> bf16 converts: ONE launch for all 7 tensors -------
struct CvtAll { const float* s[7]; unsigned short* d[7]; };

__device__ __forceinline__ void cvt_body(const float* __restrict__ s,
                                         unsigned short* __restrict__ d, int i) {
  const f32x4* sp = (const f32x4*)s + (size_t)i * 2;
  f32x4 a = sp[0], b = sp[1];
  u16x8 o;
  o[0]=f2bf(a[0]); o[1]=f2bf(a[1]); o[2]=f2bf(a[2]); o[3]=f2bf(a[3]);
  o[4]=f2bf(b[0]); o[5]=f2bf(b[1]); o[6]=f2bf(b[2]); o[7]=f2bf(b[3]);
  *((u16x8*)d + i) = o;
}

// grid 8192: q,k,v = 2048 blocks each; 4 weights = 512 each. No tails.
__global__ void cvt_all_kernel(CvtAll a) {
  int bi = blockIdx.x, seg, i;
  if (bi < 6144) { seg = bi >> 11;              i = ((bi & 2047) << 8) + threadIdx.x; }
  else           { int t = bi - 6144; seg = 3 + (t >> 9); i = ((t & 511) << 8) + threadIdx.x; }
  cvt_body(a.s[seg], a.d[seg], i);
}

// ---------------- NT GEMM body: C[m][n] = (sum_k A[m][k]*B[n][k] + bias)*scale
__device__ __forceinline__ void gemm_body(
    const unsigned short* __restrict__ A,
    const unsigned short* __restrict__ Bm,
    unsigned short* __restrict__ Obf,
    float* __restrict__ Of32,
    const float* __restrict__ bias,
    int N, int K, float scale, int biasRow, int m0, int n0)
{
  __shared__ unsigned short As[128*32];
  __shared__ unsigned short Bs[128*32];
  const int tid  = threadIdx.x;
  const int lane = tid & 63;
  const int w    = tid >> 6;
  const int wm   = w >> 1, wn = w & 1;
  const int fr   = lane & 15, kg = lane >> 4;

  f32x4 acc[4][4];
  #pragma unroll
  for (int i = 0; i < 4; ++i)
    #pragma unroll
    for (int j = 0; j < 4; ++j)
      acc[i][j] = (f32x4)0.0f;

  const int o0 = tid * 16,        o1 = (256 + tid) * 16;
  const int r0 = o0 >> 6,         c0 = (o0 & 63) >> 1;
  const int r1 = o1 >> 6,         c1 = (o1 & 63) >> 1;
  const int lds0 = (w * 64) * 16;
  const int lds1 = (256 + w * 64) * 16;

  const int nkt = K >> 5;
  for (int kt = 0; kt < nkt; ++kt) {
    const int kk = kt * 32;
    __builtin_amdgcn_global_load_lds((GU32*)(A  + (size_t)(m0 + r0) * K + kk + c0),
                                     (LU32*)((char*)As + lds0), 16, 0, 0);
    __builtin_amdgcn_global_load_lds((GU32*)(A  + (size_t)(m0 + r1) * K + kk + c1),
                                     (LU32*)((char*)As + lds1), 16, 0, 0);
    __builtin_amdgcn_global_load_lds((GU32*)(Bm + (size_t)(n0 + r0) * K + kk + c0),
                                     (LU32*)((char*)Bs + lds0), 16, 0, 0);
    __builtin_amdgcn_global_load_lds((GU32*)(Bm + (size_t)(n0 + r1) * K + kk + c1),
                                     (LU32*)((char*)Bs + lds1), 16, 0, 0);
    __syncthreads();

    bf16x8 af[4], bf[4];
    #pragma unroll
    for (int i = 0; i < 4; ++i)
      af[i] = *(const bf16x8*)&As[(wm * 64 + i * 16 + fr) * 32 + kg * 8];
    #pragma unroll
    for (int j = 0; j < 4; ++j)
      bf[j] = *(const bf16x8*)&Bs[(wn * 64 + j * 16 + fr) * 32 + kg * 8];
    #pragma unroll
    for (int i = 0; i < 4; ++i)
      #pragma unroll
      for (int j = 0; j < 4; ++j)
        acc[i][j] = __builtin_amdgcn_mfma_f32_16x16x32_bf16(af[i], bf[j], acc[i][j], 0, 0, 0);
    __syncthreads();
  }

  #pragma unroll
  for (int i = 0; i < 4; ++i) {
    const int rowb = m0 + wm * 64 + i * 16 + kg * 4;
    #pragma unroll
    for (int j = 0; j < 4; ++j) {
      const int col = n0 + wn * 64 + j * 16 + fr;
      const float bcol = biasRow ? 0.0f : bias[col];
      #pragma unroll
      for (int r = 0; r < 4; ++r) {
        const int row = rowb + r;
        const float bv = biasRow ? bias[row] : bcol;
        const float val = (acc[i][j][r] + bv) * scale;
        if (Obf) Obf[(size_t)row * N + col] = f2bf(val);
        else     Of32[(size_t)row * N + col] = val;
      }
    }
  }
}

struct GemmSet { const unsigned short* A; const unsigned short* Bm;
                 unsigned short* O; const float* bias; };

__launch_bounds__(256)
__global__ void qkv_gemm(GemmSet s0, GemmSet s1, GemmSet s2) {
  const int z = blockIdx.y;
  GemmSet s = (z == 0) ? s0 : (z == 1) ? s1 : s2;
  int m0, n0, N; float scale; int biasRow;
  if (z < 2) { m0 = (blockIdx.x & 31) * 128; n0 = (blockIdx.x >> 5) * 128;
               N = D_; scale = (z == 0) ? 0.125f : 1.0f; biasRow = 0; }
  else       { m0 = (blockIdx.x & 7) * 128;  n0 = (blockIdx.x >> 3) * 128;
               N = M_; scale = 1.0f; biasRow = 1; }
  gemm_body(s.A, s.Bm, s.O, nullptr, s.bias, N, D_, scale, biasRow, m0, n0);
}

__launch_bounds__(256)
__global__ void dense_gemm(const unsigned short* __restrict__ A,
                           const unsigned short* __restrict__ Bm,
                           float* __restrict__ O, const float* __restrict__ bias) {
  gemm_body(A, Bm, nullptr, O, bias, D_, D_, 1.0f, 0,
            blockIdx.x * 128, blockIdx.y * 128);
}

// ---------------- fused attention v8: per-wave autonomy, 0 loop barriers ---
// (v7 + LDS map fix: ssum no longer overlaps the wave staging regions.)
// grid 2048 blocks, 512 threads (8 waves). Per block: 32 q-rows, k = 1024.
// Each wave owns k-strip [w*128, w*128+128) and a PRIVATE 8KB LDS region; it
// stages its own K/adjoin/V tiles with global_load_lds and waits with its own
// counted vmcnt — no __syncthreads in any loop. Only 2 block barriers total.
// LDS map: P [0,64K) | mask [64K,68K) | ssum [68K+2048=69632, 70656) |
//          wave regions [70656, 136192).
__launch_bounds__(512, 2)
__global__ void attn_kernel(const unsigned short* __restrict__ qp,
                            const unsigned short* __restrict__ kp,
                            const unsigned short* __restrict__ vt,
                            const float* __restrict__ mask,
                            const float* __restrict__ adjoin,
                            float* __restrict__ attn_out,
                            unsigned short* __restrict__ ctx)
{
  __shared__ __align__(16) char L[136192];
  char* const Pb  = L;                       // P bf16 [32][2048B], XOR-swizzled
  char* const Mbb = L + 65536;               // mask f32 [1024]
  float* const ssum = (float*)(L + 69632);   // [32][8] = 1024B, ends 70656

  const int tid = threadIdx.x, lane = tid & 63, w = tid >> 6;
  const int fr = lane & 15, kg = lane >> 4;
  const int fm = w >> 2, fd = w & 3;
  const int frsw = (fr & 7) << 4;
  const int r8 = lane >> 3;                  // staging row-within-8
  const int c7p = (((lane & 7) ^ r8) << 4);  // staging swizzled col bytes

  char* const Wb  = L + 70656 + w * 8192;    // per-wave region [70656,136192)
  char* const Ks0 = Wb,        * const Ks1 = Wb + 2048;
  char* const As0 = Wb + 4096, * const As1 = Wb + 6144;   // adj, reused for V

  // XCD map: XCD x=i&7 owns bh in [8x,8x+8); adjoin tile reused by 8 heads.
  const int i_ = blockIdx.x;
  const int bh = (i_ & 7) * 8 + ((i_ >> 3) & 7);
  const int qt = i_ >> 6;
  const int b = bh >> 4, h = bh & 15;
  const int q0 = qt * 32;
  const int kw = w * 128;                    // wave k-strip base

  const char* kG = (const char*)(kp + (size_t)b * S_ * D_ + h * DEPTH_);
  const char* aG = (const char*)(adjoin + (size_t)b * S_ * S_ + (size_t)q0 * S_);
  const char* vG = (const char*)(vt + (size_t)h * DEPTH_ * M_ + (size_t)b * S_);
  const char* mG = (const char*)(mask + (size_t)b * S_);

  auto stageK = [&](int t, char* dst) {
    #pragma unroll
    for (int j = 0; j < 2; ++j)
      __builtin_amdgcn_global_load_lds(
          (GU32*)(kG + (size_t)(kw + t * 16 + j * 8 + r8) * 2048 + c7p),
          (LU32*)(dst + j * 1024 + lane * 16), 16, 0, 0);
  };
  auto stageA = [&](int t, char* dst) {
    #pragma unroll
    for (int j = 0; j < 2; ++j) {
      const int qA = j * 8 + r8 + ((c7p >> 6) << 4);
      __builtin_amdgcn_global_load_lds(
          (GU32*)(aG + (size_t)qA * 4096 + kw * 4 + t * 64 + (c7p & 63)),
          (LU32*)(dst + j * 1024 + lane * 16), 16, 0, 0);
    }
  };
  auto stageV = [&](int t, char* dst) {
    #pragma unroll
    for (int j = 0; j < 2; ++j)
      __builtin_amdgcn_global_load_lds(
          (GU32*)(vG + (size_t)(fd * 16 + j * 8 + r8) * 8192 + t * 128 + c7p),
          (LU32*)(dst + j * 1024 + lane * 16), 16, 0, 0);
  };

  // ---- Q register loads FIRST (oldest in vmcnt queue)
  const unsigned short* q0p = qp + ((size_t)b * S_ + q0 + fr) * D_ + h * DEPTH_;
  const unsigned short* q1p = q0p + 16 * D_;
  bf16x8 qf00 = *(const bf16x8*)&q0p[kg * 8];
  bf16x8 qf01 = *(const bf16x8*)&q0p[32 + kg * 8];
  bf16x8 qf10 = *(const bf16x8*)&q1p[kg * 8];
  bf16x8 qf11 = *(const bf16x8*)&q1p[32 + kg * 8];

  // ---- prologue staging: [w<4: mask 1KB], K0, A0, K1, A1
  if (w < 4)
    __builtin_amdgcn_global_load_lds((GU32*)(mG + (w << 10) + lane * 16),
                                     (LU32*)(Mbb + (w << 10) + lane * 16), 16, 0, 0);
  stageK(0, Ks0); stageA(0, As0);
  stageK(1, Ks1); stageA(1, As1);
  asm volatile("s_waitcnt vmcnt(4)" ::: "memory");   // Q, mask, K0, A0 done
  __builtin_amdgcn_s_barrier();                      // mask visible to all
  __builtin_amdgcn_sched_barrier(0);

  float ls0 = 0.0f, ls1 = 0.0f;

  // ---- QK loop: 8 per-wave iterations, no barriers
  #pragma unroll
  for (int t = 0; t < 8; ++t) {
    if (t == 7) asm volatile("s_waitcnt vmcnt(2)" ::: "memory");
    else        asm volatile("s_waitcnt vmcnt(4)" ::: "memory");
    __builtin_amdgcn_sched_barrier(0);

    const char* kb = (t & 1) ? Ks1 : Ks0;
    const char* ab = (t & 1) ? As1 : As0;
    bf16x8 kf0 = *(const bf16x8*)(kb + fr * 128 + ((kg * 16) ^ frsw));
    bf16x8 kf1 = *(const bf16x8*)(kb + fr * 128 + ((64 + kg * 16) ^ frsw));
    f32x4 a40 = *(const f32x4*)(ab + fr * 128 + ((kg * 16) ^ frsw));
    f32x4 a41 = *(const f32x4*)(ab + fr * 128 + ((64 + kg * 16) ^ frsw));
    f32x4 m4  = *(const f32x4*)(Mbb + kw * 4 + t * 64 + kg * 16);

    asm volatile("s_waitcnt lgkmcnt(0)" ::: "memory");  // buffers free
    __builtin_amdgcn_sched_barrier(0);

    if (t < 6)      { stageK(t + 2, (t & 1) ? Ks1 : Ks0);
                      stageA(t + 2, (t & 1) ? As1 : As0); }
    else if (t == 6)  stageV(0, As0);   // A6's buffer, just consumed
    else              stageV(1, As1);   // A7's buffer

    f32x4 s0 = (f32x4)0.0f, s1 = (f32x4)0.0f;
    s0 = __builtin_amdgcn_mfma_f32_16x16x32_bf16(kf0, qf00, s0, 0, 0, 0);
    s0 = __builtin_amdgcn_mfma_f32_16x16x32_bf16(kf1, qf01, s0, 0, 0, 0);
    s1 = __builtin_amdgcn_mfma_f32_16x16x32_bf16(kf0, qf10, s1, 0, 0, 0);
    s1 = __builtin_amdgcn_mfma_f32_16x16x32_bf16(kf1, qf11, s1, 0, 0, 0);

    f32x4 p0, p1;
    #pragma unroll
    for (int r = 0; r < 4; ++r) {
      p0[r] = __expf(s0[r] + a40[r] + m4[r] * (-1e9f));
      p1[r] = __expf(s1[r] + a41[r] + m4[r] * (-1e9f));
    }
    ls0 += (p0[0] + p0[1]) + (p0[2] + p0[3]);
    ls1 += (p1[0] + p1[1]) + (p1[2] + p1[3]);
    u16x4 pk0, pk1;
    #pragma unroll
    for (int r = 0; r < 4; ++r) { pk0[r] = f2bf(p0[r]); pk1[r] = f2bf(p1[r]); }
    const int pcol = (kw * 2 + t * 32 + kg * 8) ^ frsw;
    *(u16x4*)(Pb + fr * 2048 + pcol)        = pk0;
    *(u16x4*)(Pb + (16 + fr) * 2048 + pcol) = pk1;
  }

  // ---- strip sums -> ssum
  ls0 += __shfl_xor(ls0, 16); ls0 += __shfl_xor(ls0, 32);
  ls1 += __shfl_xor(ls1, 16); ls1 += __shfl_xor(ls1, 32);
  if (lane < 16) {
    ssum[lane * 8 + w]        = ls0;
    ssum[(16 + lane) * 8 + w] = ls1;
  }

  // ---- single mid barrier: P + ssum visible; V0,V1 still in flight
  asm volatile("s_waitcnt lgkmcnt(0)" ::: "memory");
  __builtin_amdgcn_s_barrier();
  __builtin_amdgcn_sched_barrier(0);

  // ---- PV loop: 16 per-wave iterations, no barriers
  const int q = fm * 16 + fr;
  f32x4 cacc = (f32x4)0.0f;
  #pragma unroll
  for (int t = 0; t < 16; ++t) {
    if (t == 15) asm volatile("s_waitcnt vmcnt(0)" ::: "memory");
    else         asm volatile("s_waitcnt vmcnt(2)" ::: "memory");
    __builtin_amdgcn_sched_barrier(0);

    const char* vb = (t & 1) ? As1 : As0;
    bf16x8 vf0 = *(const bf16x8*)(vb + fr * 128 + ((kg * 16) ^ frsw));
    bf16x8 vf1 = *(const bf16x8*)(vb + fr * 128 + ((64 + kg * 16) ^ frsw));
    bf16x8 pf0 = *(const bf16x8*)(Pb + q * 2048 + ((t * 128 + kg * 16) ^ frsw));
    bf16x8 pf1 = *(const bf16x8*)(Pb + q * 2048 + ((t * 128 + 64 + kg * 16) ^ frsw));

    asm volatile("s_waitcnt lgkmcnt(0)" ::: "memory");
    __builtin_amdgcn_sched_barrier(0);

    if (t < 14) stageV(t + 2, (t & 1) ? As1 : As0);

    cacc = __builtin_amdgcn_mfma_f32_16x16x32_bf16(vf0, pf0, cacc, 0, 0, 0);
    cacc = __builtin_amdgcn_mfma_f32_16x16x32_bf16(vf1, pf1, cacc, 0, 0, 0);
  }

  // ---- ctx store (normal store; re-read by dense_gemm)
  {
    f32x4 sa = *(const f32x4*)&ssum[q * 8];
    f32x4 sb = *(const f32x4*)&ssum[q * 8 + 4];
    const float giC = 1.0f / ((sa[0] + sa[1]) + (sa[2] + sa[3]) +
                              ((sb[0] + sb[1]) + (sb[2] + sb[3])));
    u16x4 cv;
    #pragma unroll
    for (int r = 0; r < 4; ++r) cv[r] = f2bf(cacc[r] * giC);
    *(u16x4*)&ctx[((size_t)b * S_ + q0 + q) * D_ + h * DEPTH_ + fd * 16 + kg * 4] = cv;
  }

  // ---- attn store: 4 rows/wave from P-LDS, nontemporal full-line stores
  #pragma unroll
  for (int j = 0; j < 4; ++j) {
    const int row = w * 4 + j;
    f32x4 ta = *(const f32x4*)&ssum[row * 8];
    f32x4 tb = *(const f32x4*)&ssum[row * 8 + 4];
    const float g = 1.0f / ((ta[0] + ta[1]) + (ta[2] + ta[3]) +
                            ((tb[0] + tb[1]) + (tb[2] + tb[3])));
    const char* pr = Pb + row * 2048;
    const int rs = (row & 7) << 4;
    float* ao = attn_out + ((size_t)bh * S_ + q0 + row) * S_;
    #pragma unroll
    for (int half = 0; half < 2; ++half) {
      u16x8 pv = *(const u16x8*)(pr + ((half * 1024 + lane * 16) ^ rs));
      f32x4 o0, o1;
      #pragma unroll
      for (int e = 0; e < 4; ++e) { o0[e] = bf2f(pv[e]) * g; o1[e] = bf2f(pv[4 + e]) * g; }
      __builtin_nontemporal_store(o0, (f32x4*)(ao + half * 512 + lane * 8));
      __builtin_nontemporal_store(o1, (f32x4*)(ao + half * 512 + lane * 8 + 4));
    }
  }
}

// ---------------- launcher ----------------
extern "C" void kernel_launch(void* const* d_in, const int* in_sizes, int n_in,
                              void* d_out, int out_size, void* d_ws, size_t ws_size,
                              hipStream_t stream)
{
  const float* v_in   = (const float*)d_in[0];
  const float* k_in   = (const float*)d_in[1];
  const float* q_in   = (const float*)d_in[2];
  const float* mask   = (const float*)d_in[3];
  const float* adjoin = (const float*)d_in[4];
  const float* wq_w   = (const float*)d_in[5];
  const float* wq_b   = (const float*)d_in[6];
  const float* wk_w   = (const float*)d_in[7];
  const float* wk_b   = (const float*)d_in[8];
  const float* wv_w   = (const float*)d_in[9];
  const float* wv_b   = (const float*)d_in[10];
  const float* wd_w   = (const float*)d_in[11];
  const float* wd_b   = (const float*)d_in[12];

  unsigned short* xq  = (unsigned short*)d_ws;
  unsigned short* xk  = xq  + (size_t)M_ * D_;
  unsigned short* xv  = xk  + (size_t)M_ * D_;
  unsigned short* wqb = xv  + (size_t)M_ * D_;
  unsigned short* wkb = wqb + (size_t)D_ * D_;
  unsigned short* wvb = wkb + (size_t)D_ * D_;
  unsigned short* wdb = wvb + (size_t)D_ * D_;
  unsigned short* qp  = wdb + (size_t)D_ * D_;
  unsigned short* kp  = qp  + (size_t)M_ * D_;
  unsigned short* vt  = kp  + (size_t)M_ * D_;
  unsigned short* ctx = vt  + (size_t)M_ * D_;

  float* out  = (float*)d_out;                       // [B,S,D]
  float* attn = out + (size_t)B_ * S_ * D_;          // [B,H,S,S]

  CvtAll ca;
  ca.s[0] = q_in; ca.s[1] = k_in; ca.s[2] = v_in;
  ca.s[3] = wq_w; ca.s[4] = wk_w; ca.s[5] = wv_w; ca.s[6] = wd_w;
  ca.d[0] = xq;   ca.d[1] = xk;   ca.d[2] = xv;
  ca.d[3] = wqb;  ca.d[4] = wkb;  ca.d[5] = wvb;  ca.d[6] = wdb;
  cvt_all_kernel<<<8192, 256, 0, stream>>>(ca);

  GemmSet sq{xq,  wqb, qp, wq_b};
  GemmSet sk{xk,  wkb, kp, wk_b};
  GemmSet sv{wvb, xv,  vt, wv_b};
  qkv_gemm<<<dim3(256, 3), 256, 0, stream>>>(sq, sk, sv);

  attn_kernel<<<B_ * H_ * (S_ / 32), 512, 0, stream>>>(qp, kp, vt, mask, adjoin, attn, ctx);

  dense_gemm<<<dim3(32, 8), 256, 0, stream>>>(ctx, wdb, out, wd_b);
}

// Round 9
// 186.650 us; speedup vs baseline: 1.2881x; 1.0540x over previous
//
#include <hip/hip_runtime.h>
#include <hip/hip_bf16.h>
#include <cstdint>
#include <cstddef>

#define B_ 4
#define S_ 1024
#define D_ 1024
#define H_ 16
#define DEPTH_ 64
#define M_ (B_*S_)   // 4096 rows total

typedef __attribute__((ext_vector_type(4))) float f32x4;
typedef __attribute__((ext_vector_type(8))) __bf16 bf16x8;
typedef __attribute__((ext_vector_type(8))) unsigned short u16x8;
typedef __attribute__((ext_vector_type(4))) unsigned short u16x4;

typedef const __attribute__((address_space(1))) unsigned int GU32;
typedef __attribute__((address_space(3))) unsigned int LU32;

__device__ __forceinline__ unsigned short f2bf(float f) {
  unsigned int u = __builtin_bit_cast(unsigned int, f);
  u += 0x7FFFu + ((u >> 16) & 1u);   // round-to-nearest-even
  return (unsigned short)(u >> 16);
}

__device__ __forceinline__ float bf2f(unsigned short v) {
  unsigned int u = (unsigned int)v << 16;
  return __builtin_bit_cast(float, u);
}

// ---------------- f32 -> bf16 converts: ONE launch for all 7 tensors -------
struct CvtAll { const float* s[7]; unsigned short* d[7]; };

__device__ __forceinline__ void cvt_body(const float* __restrict__ s,
                                         unsigned short* __restrict__ d, int i) {
  const f32x4* sp = (const f32x4*)s + (size_t)i * 2;
  f32x4 a = sp[0], b = sp[1];
  u16x8 o;
  o[0]=f2bf(a[0]); o[1]=f2bf(a[1]); o[2]=f2bf(a[2]); o[3]=f2bf(a[3]);
  o[4]=f2bf(b[0]); o[5]=f2bf(b[1]); o[6]=f2bf(b[2]); o[7]=f2bf(b[3]);
  *((u16x8*)d + i) = o;
}

// grid 8192: q,k,v = 2048 blocks each; 4 weights = 512 each. No tails.
__global__ void cvt_all_kernel(CvtAll a) {
  int bi = blockIdx.x, seg, i;
  if (bi < 6144) { seg = bi >> 11;              i = ((bi & 2047) << 8) + threadIdx.x; }
  else           { int t = bi - 6144; seg = 3 + (t >> 9); i = ((t & 511) << 8) + threadIdx.x; }
  cvt_body(a.s[seg], a.d[seg], i);
}

// ---------------- NT GEMM body: C[m][n] = (sum_k A[m][k]*B[n][k] + bias)*scale
__device__ __forceinline__ void gemm_body(
    const unsigned short* __restrict__ A,
    const unsigned short* __restrict__ Bm,
    unsigned short* __restrict__ Obf,
    float* __restrict__ Of32,
    const float* __restrict__ bias,
    int N, int K, float scale, int biasRow, int m0, int n0)
{
  __shared__ unsigned short As[128*32];
  __shared__ unsigned short Bs[128*32];
  const int tid  = threadIdx.x;
  const int lane = tid & 63;
  const int w    = tid >> 6;
  const int wm   = w >> 1, wn = w & 1;
  const int fr   = lane & 15, kg = lane >> 4;

  f32x4 acc[4][4];
  #pragma unroll
  for (int i = 0; i < 4; ++i)
    #pragma unroll
    for (int j = 0; j < 4; ++j)
      acc[i][j] = (f32x4)0.0f;

  const int o0 = tid * 16,        o1 = (256 + tid) * 16;
  const int r0 = o0 >> 6,         c0 = (o0 & 63) >> 1;
  const int r1 = o1 >> 6,         c1 = (o1 & 63) >> 1;
  const int lds0 = (w * 64) * 16;
  const int lds1 = (256 + w * 64) * 16;

  const int nkt = K >> 5;
  for (int kt = 0; kt < nkt; ++kt) {
    const int kk = kt * 32;
    __builtin_amdgcn_global_load_lds((GU32*)(A  + (size_t)(m0 + r0) * K + kk + c0),
                                     (LU32*)((char*)As + lds0), 16, 0, 0);
    __builtin_amdgcn_global_load_lds((GU32*)(A  + (size_t)(m0 + r1) * K + kk + c1),
                                     (LU32*)((char*)As + lds1), 16, 0, 0);
    __builtin_amdgcn_global_load_lds((GU32*)(Bm + (size_t)(n0 + r0) * K + kk + c0),
                                     (LU32*)((char*)Bs + lds0), 16, 0, 0);
    __builtin_amdgcn_global_load_lds((GU32*)(Bm + (size_t)(n0 + r1) * K + kk + c1),
                                     (LU32*)((char*)Bs + lds1), 16, 0, 0);
    __syncthreads();

    bf16x8 af[4], bf[4];
    #pragma unroll
    for (int i = 0; i < 4; ++i)
      af[i] = *(const bf16x8*)&As[(wm * 64 + i * 16 + fr) * 32 + kg * 8];
    #pragma unroll
    for (int j = 0; j < 4; ++j)
      bf[j] = *(const bf16x8*)&Bs[(wn * 64 + j * 16 + fr) * 32 + kg * 8];
    #pragma unroll
    for (int i = 0; i < 4; ++i)
      #pragma unroll
      for (int j = 0; j < 4; ++j)
        acc[i][j] = __builtin_amdgcn_mfma_f32_16x16x32_bf16(af[i], bf[j], acc[i][j], 0, 0, 0);
    __syncthreads();
  }

  #pragma unroll
  for (int i = 0; i < 4; ++i) {
    const int rowb = m0 + wm * 64 + i * 16 + kg * 4;
    #pragma unroll
    for (int j = 0; j < 4; ++j) {
      const int col = n0 + wn * 64 + j * 16 + fr;
      const float bcol = biasRow ? 0.0f : bias[col];
      #pragma unroll
      for (int r = 0; r < 4; ++r) {
        const int row = rowb + r;
        const float bv = biasRow ? bias[row] : bcol;
        const float val = (acc[i][j][r] + bv) * scale;
        if (Obf) Obf[(size_t)row * N + col] = f2bf(val);
        else     Of32[(size_t)row * N + col] = val;
      }
    }
  }
}

struct GemmSet { const unsigned short* A; const unsigned short* Bm;
                 unsigned short* O; const float* bias; };

__launch_bounds__(256)
__global__ void qkv_gemm(GemmSet s0, GemmSet s1, GemmSet s2) {
  const int z = blockIdx.y;
  GemmSet s = (z == 0) ? s0 : (z == 1) ? s1 : s2;
  int m0, n0, N; float scale; int biasRow;
  if (z < 2) { m0 = (blockIdx.x & 31) * 128; n0 = (blockIdx.x >> 5) * 128;
               N = D_; scale = (z == 0) ? 0.125f : 1.0f; biasRow = 0; }
  else       { m0 = (blockIdx.x & 7) * 128;  n0 = (blockIdx.x >> 3) * 128;
               N = M_; scale = 1.0f; biasRow = 1; }
  gemm_body(s.A, s.Bm, s.O, nullptr, s.bias, N, D_, scale, biasRow, m0, n0);
}

__launch_bounds__(256)
__global__ void dense_gemm(const unsigned short* __restrict__ A,
                           const unsigned short* __restrict__ Bm,
                           float* __restrict__ O, const float* __restrict__ bias) {
  gemm_body(A, Bm, nullptr, O, bias, D_, D_, 1.0f, 0,
            blockIdx.x * 128, blockIdx.y * 128);
}

// ---------------- fused attention v9: per-wave autonomy, 2 blocks/CU -------
// grid 4096 blocks, 512 threads (8 waves). Per block: 16 q-rows, k = 1024.
// QK: wave w owns k-strip [w*128,(w+1)*128), 8 iters of 16k, private dbuf.
// PV: wave w -> (d-tile fd=w&3, k-half kh=w>>2), 8 iters of 64k; partials of
// waves 4-7 reduced by waves 0-3 through LDS. Mask lives in registers.
// Barriers: 1 mid (P/ssum), 1 epilogue (PV partials). None in loops.
// LDS 80KB exact: P [0,32K) | 8 regions x 6KB [32K,80K):
//   region: K0 2K | K1 2K | A0 1K (-> ssum) | A1 1K (-> PV partials)
__launch_bounds__(512, 4)
__global__ void attn_kernel(const unsigned short* __restrict__ qp,
                            const unsigned short* __restrict__ kp,
                            const unsigned short* __restrict__ vt,
                            const float* __restrict__ mask,
                            const float* __restrict__ adjoin,
                            float* __restrict__ attn_out,
                            unsigned short* __restrict__ ctx)
{
  __shared__ __align__(16) char L[81920];
  char* const Pb = L;                       // P bf16 [16][2048B], XOR-swizzled
  char* const Rg = L + 32768;               // 8 x 6144B wave regions

  const int tid = threadIdx.x, lane = tid & 63, w = tid >> 6;
  const int fr = lane & 15, kg = lane >> 4;
  const int fd = w & 3, kh = w >> 2;
  const int frsw = (fr & 7) << 4;
  const int r8 = lane >> 3;
  const int c7p = (((lane & 7) ^ r8) << 4);

  char* const Wb  = Rg + w * 6144;
  char* const Ks0 = Wb,        * const Ks1 = Wb + 2048;
  char* const Ab0 = Wb + 4096, * const Ab1 = Wb + 5120;

  // XCD map: XCD x=i&7 owns bh in [8x,8x+8); adjoin tile reused by 8 heads.
  const int i_ = blockIdx.x;
  const int bh = (i_ & 7) * 8 + ((i_ >> 3) & 7);
  const int qt = i_ >> 6;
  const int b = bh >> 4, h = bh & 15;
  const int q0 = qt * 16;
  const int kw = w * 128;                   // wave k-strip base

  const char* kG = (const char*)(kp + (size_t)b * S_ * D_ + h * DEPTH_);
  const char* aG = (const char*)(adjoin + (size_t)b * S_ * S_ + (size_t)q0 * S_);
  const char* vG = (const char*)(vt + (size_t)h * DEPTH_ * M_ + (size_t)b * S_);
  const char* mG = (const char*)(mask + (size_t)b * S_);

  auto stageK = [&](int t, char* dst) {
    #pragma unroll
    for (int j = 0; j < 2; ++j)
      __builtin_amdgcn_global_load_lds(
          (GU32*)(kG + (size_t)(kw + t * 16 + j * 8 + r8) * 2048 + c7p),
          (LU32*)(dst + j * 1024 + lane * 16), 16, 0, 0);
  };
  auto stageA = [&](int t, char* dst) {   // 16q x 16k f32, row=64B, linear
    __builtin_amdgcn_global_load_lds(
        (GU32*)(aG + (size_t)(lane >> 2) * 4096 + kw * 4 + t * 64 + (lane & 3) * 16),
        (LU32*)(dst + lane * 16), 16, 0, 0);
  };
  auto stageV = [&](int t, char* dst) {   // 16 d-rows x 64k of this wave's kh
    #pragma unroll
    for (int j = 0; j < 2; ++j)
      __builtin_amdgcn_global_load_lds(
          (GU32*)(vG + (size_t)(fd * 16 + j * 8 + r8) * 8192 + kh * 1024 + t * 128 + c7p),
          (LU32*)(dst + j * 1024 + lane * 16), 16, 0, 0);
  };

  // ---- Q + mask register loads FIRST (oldest in vmcnt queue)
  const unsigned short* qrow = qp + ((size_t)b * S_ + q0 + fr) * D_ + h * DEPTH_;
  bf16x8 qf0 = *(const bf16x8*)&qrow[kg * 8];
  bf16x8 qf1 = *(const bf16x8*)&qrow[32 + kg * 8];
  f32x4 mreg[8];
  #pragma unroll
  for (int t = 0; t < 8; ++t)
    mreg[t] = *(const f32x4*)(mG + kw * 4 + t * 64 + kg * 16);
  asm volatile("" ::: "memory");          // pin loads before staging

  // ---- prologue staging: K0, A0, K1, A1 (3+3 loads)
  stageK(0, Ks0); stageA(0, Ab0);
  stageK(1, Ks1); stageA(1, Ab1);
  asm volatile("s_waitcnt vmcnt(3)" ::: "memory");   // Q,mask,K0,A0 done
  __builtin_amdgcn_sched_barrier(0);

  float ls = 0.0f;

  // ---- QK loop: 8 per-wave iterations, no barriers
  #pragma unroll
  for (int t = 0; t < 8; ++t) {
    if (t == 7)     asm volatile("s_waitcnt vmcnt(2)" ::: "memory");
    else if (t > 0) asm volatile("s_waitcnt vmcnt(3)" ::: "memory");
    __builtin_amdgcn_sched_barrier(0);

    const char* kb = (t & 1) ? Ks1 : Ks0;
    const char* ab = (t & 1) ? Ab1 : Ab0;
    bf16x8 kf0 = *(const bf16x8*)(kb + fr * 128 + ((kg * 16) ^ frsw));
    bf16x8 kf1 = *(const bf16x8*)(kb + fr * 128 + ((64 + kg * 16) ^ frsw));
    f32x4 a4  = *(const f32x4*)(ab + fr * 64 + kg * 16);

    asm volatile("s_waitcnt lgkmcnt(0)" ::: "memory");  // buffers free
    __builtin_amdgcn_sched_barrier(0);

    if (t < 6)      { stageK(t + 2, (t & 1) ? Ks1 : Ks0);
                      stageA(t + 2, (t & 1) ? Ab1 : Ab0); }
    else if (t == 6)  stageV(0, Ks0);   // K0 just consumed
    else              stageV(1, Ks1);   // K1 just consumed

    f32x4 s = (f32x4)0.0f;
    s = __builtin_amdgcn_mfma_f32_16x16x32_bf16(kf0, qf0, s, 0, 0, 0);
    s = __builtin_amdgcn_mfma_f32_16x16x32_bf16(kf1, qf1, s, 0, 0, 0);

    f32x4 p;
    #pragma unroll
    for (int r = 0; r < 4; ++r)
      p[r] = __expf(s[r] + a4[r] + mreg[t][r] * (-1e9f));
    ls += (p[0] + p[1]) + (p[2] + p[3]);
    u16x4 pk;
    #pragma unroll
    for (int r = 0; r < 4; ++r) pk[r] = f2bf(p[r]);
    *(u16x4*)(Pb + fr * 2048 + ((kw * 2 + t * 32 + kg * 8) ^ frsw)) = pk;
  }

  // ---- strip sums -> own A0 slot
  ls += __shfl_xor(ls, 16);
  ls += __shfl_xor(ls, 32);
  if (lane < 16) *(float*)(Ab0 + lane * 4) = ls;

  // ---- mid barrier: P + ssum visible; V0,V1 still in flight
  asm volatile("s_waitcnt lgkmcnt(0)" ::: "memory");
  __builtin_amdgcn_s_barrier();
  __builtin_amdgcn_sched_barrier(0);

  // ---- PV loop: 8 per-wave iterations of 64k, no barriers
  f32x4 cacc = (f32x4)0.0f;
  #pragma unroll
  for (int t = 0; t < 8; ++t) {
    if (t == 7) asm volatile("s_waitcnt vmcnt(0)" ::: "memory");
    else        asm volatile("s_waitcnt vmcnt(2)" ::: "memory");
    __builtin_amdgcn_sched_barrier(0);

    const char* vb = (t & 1) ? Ks1 : Ks0;
    bf16x8 vf0 = *(const bf16x8*)(vb + fr * 128 + ((kg * 16) ^ frsw));
    bf16x8 vf1 = *(const bf16x8*)(vb + fr * 128 + ((64 + kg * 16) ^ frsw));
    bf16x8 pf0 = *(const bf16x8*)(Pb + fr * 2048 + ((kh * 1024 + t * 128 + kg * 16) ^ frsw));
    bf16x8 pf1 = *(const bf16x8*)(Pb + fr * 2048 + ((kh * 1024 + t * 128 + 64 + kg * 16) ^ frsw));

    asm volatile("s_waitcnt lgkmcnt(0)" ::: "memory");
    __builtin_amdgcn_sched_barrier(0);

    if (t < 6) stageV(t + 2, (t & 1) ? Ks1 : Ks0);

    cacc = __builtin_amdgcn_mfma_f32_16x16x32_bf16(vf0, pf0, cacc, 0, 0, 0);
    cacc = __builtin_amdgcn_mfma_f32_16x16x32_bf16(vf1, pf1, cacc, 0, 0, 0);
  }

  // ---- epilogue: waves 4-7 publish k-half partials; 0-3 reduce + ctx
  if (w >= 4) *(f32x4*)(Ab1 + lane * 16) = cacc;
  asm volatile("s_waitcnt lgkmcnt(0)" ::: "memory");
  __builtin_amdgcn_s_barrier();
  __builtin_amdgcn_sched_barrier(0);

  if (w < 4) {
    f32x4 red = *(const f32x4*)(Rg + (w + 4) * 6144 + 5120 + lane * 16);
    #pragma unroll
    for (int r = 0; r < 4; ++r) cacc[r] += red[r];
    float gs = 0.0f;
    #pragma unroll
    for (int w2 = 0; w2 < 8; ++w2)
      gs += *(const float*)(Rg + w2 * 6144 + 4096 + fr * 4);
    const float giC = 1.0f / gs;
    u16x4 cv;
    #pragma unroll
    for (int r = 0; r < 4; ++r) cv[r] = f2bf(cacc[r] * giC);
    *(u16x4*)&ctx[((size_t)b * S_ + q0 + fr) * D_ + h * DEPTH_ + fd * 16 + kg * 4] = cv;
  }

  // ---- attn store: 2 rows/wave from P-LDS, nontemporal full-line stores
  #pragma unroll
  for (int j = 0; j < 2; ++j) {
    const int row = w * 2 + j;
    float gs = 0.0f;
    #pragma unroll
    for (int w2 = 0; w2 < 8; ++w2)
      gs += *(const float*)(Rg + w2 * 6144 + 4096 + row * 4);
    const float g = 1.0f / gs;
    const char* pr = Pb + row * 2048;
    const int rs = (row & 7) << 4;
    float* ao = attn_out + ((size_t)bh * S_ + q0 + row) * S_;
    #pragma unroll
    for (int half = 0; half < 2; ++half) {
      u16x8 pv = *(const u16x8*)(pr + ((half * 1024 + lane * 16) ^ rs));
      f32x4 o0, o1;
      #pragma unroll
      for (int e = 0; e < 4; ++e) { o0[e] = bf2f(pv[e]) * g; o1[e] = bf2f(pv[4 + e]) * g; }
      __builtin_nontemporal_store(o0, (f32x4*)(ao + half * 512 + lane * 8));
      __builtin_nontemporal_store(o1, (f32x4*)(ao + half * 512 + lane * 8 + 4));
    }
  }
}

// ---------------- launcher ----------------
extern "C" void kernel_launch(void* const* d_in, const int* in_sizes, int n_in,
                              void* d_out, int out_size, void* d_ws, size_t ws_size,
                              hipStream_t stream)
{
  const float* v_in   = (const float*)d_in[0];
  const float* k_in   = (const float*)d_in[1];
  const float* q_in   = (const float*)d_in[2];
  const float* mask   = (const float*)d_in[3];
  const float* adjoin = (const float*)d_in[4];
  const float* wq_w   = (const float*)d_in[5];
  const float* wq_b   = (const float*)d_in[6];
  const float* wk_w   = (const float*)d_in[7];
  const float* wk_b   = (const float*)d_in[8];
  const float* wv_w   = (const float*)d_in[9];
  const float* wv_b   = (const float*)d_in[10];
  const float* wd_w   = (const float*)d_in[11];
  const float* wd_b   = (const float*)d_in[12];

  unsigned short* xq  = (unsigned short*)d_ws;
  unsigned short* xk  = xq  + (size_t)M_ * D_;
  unsigned short* xv  = xk  + (size_t)M_ * D_;
  unsigned short* wqb = xv  + (size_t)M_ * D_;
  unsigned short* wkb = wqb + (size_t)D_ * D_;
  unsigned short* wvb = wkb + (size_t)D_ * D_;
  unsigned short* wdb = wvb + (size_t)D_ * D_;
  unsigned short* qp  = wdb + (size_t)D_ * D_;
  unsigned short* kp  = qp  + (size_t)M_ * D_;
  unsigned short* vt  = kp  + (size_t)M_ * D_;
  unsigned short* ctx = vt  + (size_t)M_ * D_;

  float* out  = (float*)d_out;                       // [B,S,D]
  float* attn = out + (size_t)B_ * S_ * D_;          // [B,H,S,S]

  CvtAll ca;
  ca.s[0] = q_in; ca.s[1] = k_in; ca.s[2] = v_in;
  ca.s[3] = wq_w; ca.s[4] = wk_w; ca.s[5] = wv_w; ca.s[6] = wd_w;
  ca.d[0] = xq;   ca.d[1] = xk;   ca.d[2] = xv;
  ca.d[3] = wqb;  ca.d[4] = wkb;  ca.d[5] = wvb;  ca.d[6] = wdb;
  cvt_all_kernel<<<8192, 256, 0, stream>>>(ca);

  GemmSet sq{xq,  wqb, qp, wq_b};
  GemmSet sk{xk,  wkb, kp, wk_b};
  GemmSet sv{wvb, xv,  vt, wv_b};
  qkv_gemm<<<dim3(256, 3), 256, 0, stream>>>(sq, sk, sv);

  attn_kernel<<<B_ * H_ * (S_ / 16), 512, 0, stream>>>(qp, kp, vt, mask, adjoin, attn, ctx);

  dense_gemm<<<dim3(32, 8), 256, 0, stream>>>(ctx, wdb, out, wd_b);
}